// Round 3
// baseline (1012.856 us; speedup 1.0000x reference)
//
#include <hip/hip_runtime.h>
#include <hip/hip_bf16.h>

// DigitCaps dynamic routing, recompute-u_hat strategy (never materialize 377MB).
// B=512 batch, I=1152 in-caps, Q=8 in-size, O=10 out-caps, P=16 out-size.
// OUTPUT IS FP32 (reference returns float32; harness reads d_out as np.float32).
#define B 512
#define IC 1152
#define QD 8
#define OD 10
#define PD 16
#define NCS 36            // i-chunks for s kernel (split-K), 1152/36 = 32 i per chunk
#define CSI (IC / NCS)
#define NCB 8             // b-chunks for agreement kernel, 512/8 = 64 b per chunk
#define SOP (B * OD * PD) // 81920 s/v elements
#define NROW (B * OD)     // 5120 (b,o) rows

// zero s accumulator and write uniform softmax c = 1/1152 (softmax of zero bij)
__global__ __launch_bounds__(256) void init_kernel(float* __restrict__ s,
                                                   float* __restrict__ c) {
  const int t = blockIdx.x * 256 + threadIdx.x;
  if (t < SOP) s[t] = 0.f;
  if (t < IC * OD) c[t] = 1.0f / (float)IC;
}

__global__ __launch_bounds__(256) void zero_s_kernel(float* __restrict__ s) {
  const int t = blockIdx.x * 256 + threadIdx.x;
  if (t < SOP) s[t] = 0.f;
}

// s[b,o,p] += sum_{i in chunk} c[i,o] * sum_q W[i,o,p,q] * x[b,i,q]
// block = (32 b-lanes, 10 o), grid = (512/32, NCS); atomic split-K accumulate.
__global__ __launch_bounds__(320) void s_kernel(const float* __restrict__ x,
                                                const float* __restrict__ W,
                                                const float* __restrict__ c,
                                                float* __restrict__ s) {
  const int b = blockIdx.x * 32 + threadIdx.x;
  const int o = threadIdx.y;
  const int i0 = blockIdx.y * CSI;
  float acc[PD];
#pragma unroll
  for (int p = 0; p < PD; ++p) acc[p] = 0.f;
  for (int ii = 0; ii < CSI; ++ii) {
    const int i = i0 + ii;
    const float4* xp = (const float4*)(x + ((size_t)b * IC + i) * QD);
    const float4 xa = xp[0], xb = xp[1];
    const float ci = c[i * OD + o];
    const float4* wp = (const float4*)(W + ((size_t)i * OD + o) * PD * QD);
#pragma unroll
    for (int p = 0; p < PD; ++p) {
      const float4 w0 = wp[2 * p], w1 = wp[2 * p + 1];
      float d = w0.x * xa.x + w0.y * xa.y + w0.z * xa.z + w0.w * xa.w +
                w1.x * xb.x + w1.y * xb.y + w1.z * xb.z + w1.w * xb.w;
      acc[p] = fmaf(ci, d, acc[p]);
    }
  }
  float* sp = s + ((size_t)b * OD + o) * PD;
#pragma unroll
  for (int p = 0; p < PD; ++p) atomicAdd(&sp[p], acc[p]);
}

// squash per (b,o) row of 16: one thread per row. Writes v and (optionally) fp32 out.
__global__ __launch_bounds__(256) void squash_kernel(const float* __restrict__ s,
                                                     float* __restrict__ v,
                                                     float* __restrict__ out,
                                                     int write_out) {
  const int r = blockIdx.x * 256 + threadIdx.x;  // < 5120, row = b*10+o
  const float4* sp = (const float4*)(s + (size_t)r * PD);
  const float4 s0 = sp[0], s1 = sp[1], s2 = sp[2], s3 = sp[3];
  const float sv[PD] = {s0.x, s0.y, s0.z, s0.w, s1.x, s1.y, s1.z, s1.w,
                        s2.x, s2.y, s2.z, s2.w, s3.x, s3.y, s3.z, s3.w};
  float sq = 0.f;
#pragma unroll
  for (int p = 0; p < PD; ++p) sq += sv[p] * sv[p];
  const float norm = sqrtf(sq + 1e-8f);
  const float scale = sq / ((1.f + sq) * norm);
  float4 r0 = make_float4(sv[0] * scale, sv[1] * scale, sv[2] * scale, sv[3] * scale);
  float4 r1 = make_float4(sv[4] * scale, sv[5] * scale, sv[6] * scale, sv[7] * scale);
  float4 r2 = make_float4(sv[8] * scale, sv[9] * scale, sv[10] * scale, sv[11] * scale);
  float4 r3 = make_float4(sv[12] * scale, sv[13] * scale, sv[14] * scale, sv[15] * scale);
  float4* vp = (float4*)(v + (size_t)r * PD);
  vp[0] = r0; vp[1] = r1; vp[2] = r2; vp[3] = r3;
  if (write_out) {
    float4* op = (float4*)(out + (size_t)r * PD);
    op[0] = r0; op[1] = r1; op[2] = r2; op[3] = r3;
  }
}

// u_vj1[i,o] = (1/B) sum_{q,p} W[i,o,p,q] * G[q][p],  G[q][p] = sum_b x[b,i,q] v[b,o,p]
// block = (64 i-lanes, 5 o-waves; o looped 2x), grid = (1152/64, NCB)
__global__ __launch_bounds__(320) void agree_kernel(const float* __restrict__ x,
                                                    const float* __restrict__ W,
                                                    const float* __restrict__ v,
                                                    float* __restrict__ u_part) {
  const int i = blockIdx.x * 64 + threadIdx.x;
  const int b0 = blockIdx.y * 64;
  for (int oo = 0; oo < 2; ++oo) {
    const int o = threadIdx.y + 5 * oo;
    float G[QD][PD];
#pragma unroll
    for (int q = 0; q < QD; ++q)
#pragma unroll
      for (int p = 0; p < PD; ++p) G[q][p] = 0.f;
    for (int b = b0; b < b0 + 64; ++b) {
      const float4* vp = (const float4*)(v + ((size_t)b * OD + o) * PD);
      const float4 v0 = vp[0], v1 = vp[1], v2 = vp[2], v3 = vp[3];
      const float vs[PD] = {v0.x, v0.y, v0.z, v0.w, v1.x, v1.y, v1.z, v1.w,
                            v2.x, v2.y, v2.z, v2.w, v3.x, v3.y, v3.z, v3.w};
      const float4* xp = (const float4*)(x + ((size_t)b * IC + i) * QD);
      const float4 xa = xp[0], xb = xp[1];
      const float xs[QD] = {xa.x, xa.y, xa.z, xa.w, xb.x, xb.y, xb.z, xb.w};
#pragma unroll
      for (int q = 0; q < QD; ++q)
#pragma unroll
        for (int p = 0; p < PD; ++p) G[q][p] = fmaf(xs[q], vs[p], G[q][p]);
    }
    const float4* wp = (const float4*)(W + ((size_t)i * OD + o) * PD * QD);
    float u = 0.f;
#pragma unroll
    for (int p = 0; p < PD; ++p) {
      const float4 w0 = wp[2 * p], w1 = wp[2 * p + 1];
      u += w0.x * G[0][p] + w0.y * G[1][p] + w0.z * G[2][p] + w0.w * G[3][p] +
           w1.x * G[4][p] + w1.y * G[5][p] + w1.z * G[6][p] + w1.w * G[7][p];
    }
    u_part[((size_t)blockIdx.y * IC + i) * OD + o] = u * (1.0f / (float)B);
  }
}

// bij += sum_chunk u_part; c = softmax over i (axis 0). One block per o.
__global__ __launch_bounds__(256) void route_kernel(const float* __restrict__ u_part,
                                                    float* __restrict__ bij,
                                                    float* __restrict__ c,
                                                    int add_prev) {
  const int o = blockIdx.x;
  __shared__ float red[256];
  float val[5];
  float lmax = -1e30f;
#pragma unroll
  for (int k = 0; k < 5; ++k) {
    const int i = threadIdx.x + k * 256;
    if (i < IC) {
      float sacc = add_prev ? bij[i * OD + o] : 0.f;
#pragma unroll
      for (int ch = 0; ch < NCB; ++ch) sacc += u_part[((size_t)ch * IC + i) * OD + o];
      val[k] = sacc;
      bij[i * OD + o] = sacc;
      lmax = fmaxf(lmax, sacc);
    } else {
      val[k] = -1e30f;
    }
  }
  red[threadIdx.x] = lmax;
  __syncthreads();
  for (int st = 128; st > 0; st >>= 1) {
    if (threadIdx.x < st) red[threadIdx.x] = fmaxf(red[threadIdx.x], red[threadIdx.x + st]);
    __syncthreads();
  }
  const float gmax = red[0];
  __syncthreads();
  float lsum = 0.f;
#pragma unroll
  for (int k = 0; k < 5; ++k) {
    const int i = threadIdx.x + k * 256;
    if (i < IC) {
      val[k] = __expf(val[k] - gmax);
      lsum += val[k];
    }
  }
  red[threadIdx.x] = lsum;
  __syncthreads();
  for (int st = 128; st > 0; st >>= 1) {
    if (threadIdx.x < st) red[threadIdx.x] += red[threadIdx.x + st];
    __syncthreads();
  }
  const float inv = 1.f / red[0];
#pragma unroll
  for (int k = 0; k < 5; ++k) {
    const int i = threadIdx.x + k * 256;
    if (i < IC) c[i * OD + o] = val[k] * inv;
  }
}

extern "C" void kernel_launch(void* const* d_in, const int* in_sizes, int n_in,
                              void* d_out, int out_size, void* d_ws, size_t ws_size,
                              hipStream_t stream) {
  const float* x = (const float*)d_in[0];  // [512,1152,8] fp32
  const float* W = (const float*)d_in[1];  // [1152,10,16,8] fp32
  float* out = (float*)d_out;              // [512,10,16] fp32

  // workspace layout (fp32): 279,040 floats = 1.12 MB total
  float* ws = (float*)d_ws;
  float* s = ws;                                 // 81920
  float* v = s + SOP;                            // 81920
  float* u_part = v + SOP;                       // NCB*11520 = 92160
  float* bij = u_part + (size_t)NCB * IC * OD;   // 11520
  float* c = bij + IC * OD;                      // 11520

  const dim3 sgrid(B / 32, NCS), sblk(32, OD);
  const dim3 agrid(IC / 64, NCB), ablk(64, 5);

  init_kernel<<<SOP / 256, 256, 0, stream>>>(s, c);
  for (int iter = 0; iter < 3; ++iter) {
    s_kernel<<<sgrid, sblk, 0, stream>>>(x, W, c, s);
    squash_kernel<<<NROW / 256, 256, 0, stream>>>(s, v, out, iter == 2);
    if (iter < 2) {
      agree_kernel<<<agrid, ablk, 0, stream>>>(x, W, v, u_part);
      route_kernel<<<OD, 256, 0, stream>>>(u_part, bij, c, iter > 0);
      zero_s_kernel<<<SOP / 256, 256, 0, stream>>>(s);
    }
  }
}

// Round 4
// 385.717 us; speedup vs baseline: 2.6259x; 2.6259x over previous
//
#include <hip/hip_runtime.h>
#include <hip/hip_bf16.h>

// DigitCaps dynamic routing, recompute-u_hat strategy (never materialize 377MB).
// B=512, I=1152, Q=8, O=10, P=16. Output fp32.
// R4: split-K partials + fused reduce (NO atomics — R3 showed 94MB/dispatch of
// atomic write-through traffic = 75% of runtime), c folded into x, per-wave-
// uniform o so W/c loads become scalar s_loads.
#define B 512
#define IC 1152
#define QD 8
#define OD 10
#define PD 16
#define NCS 36            // i-chunks for s split-K; 1152/36 = 32 i per chunk
#define CSI (IC / NCS)
#define NCB 8             // b-chunks for agreement kernel
#define SOP (B * OD * PD) // 81920 s/v elements

// c = softmax of zero bij = uniform 1/1152
__global__ __launch_bounds__(256) void init_c_kernel(float* __restrict__ c) {
  const int t = blockIdx.x * 256 + threadIdx.x;
  if (t < IC * OD) c[t] = 1.0f / (float)IC;
}

// s_part[chunk][b][o][p] = sum_{i in chunk} c[i,o] * sum_q W[i,o,p,q] * x[b,i,q]
// block = (64 b-lanes, 5 o), grid = (B/64, 2, NCS). Each wave: one uniform o.
__global__ __launch_bounds__(320) void s_kernel(const float* __restrict__ x,
                                                const float* __restrict__ W,
                                                const float* __restrict__ c,
                                                float* __restrict__ s_part) {
  const int b = blockIdx.x * 64 + threadIdx.x;
  const int o = threadIdx.y + 5 * blockIdx.y;
  const int chunk = blockIdx.z;
  const int i0 = chunk * CSI;
  float acc[PD];
#pragma unroll
  for (int p = 0; p < PD; ++p) acc[p] = 0.f;
  for (int ii = 0; ii < CSI; ++ii) {
    const int i = i0 + ii;
    // (i,o) is wave-uniform: force SGPR so W/c go through scalar loads
    const int io = __builtin_amdgcn_readfirstlane(i * OD + o);
    const float ci = c[io];
    const float4* xp = (const float4*)(x + ((size_t)b * IC + i) * QD);
    float4 xa = xp[0], xb = xp[1];
    xa.x *= ci; xa.y *= ci; xa.z *= ci; xa.w *= ci;
    xb.x *= ci; xb.y *= ci; xb.z *= ci; xb.w *= ci;
    const float4* wp = (const float4*)(W + (size_t)io * (PD * QD));
#pragma unroll
    for (int p = 0; p < PD; ++p) {
      const float4 w0 = wp[2 * p], w1 = wp[2 * p + 1];
      acc[p] = fmaf(w0.x, xa.x, acc[p]);
      acc[p] = fmaf(w0.y, xa.y, acc[p]);
      acc[p] = fmaf(w0.z, xa.z, acc[p]);
      acc[p] = fmaf(w0.w, xa.w, acc[p]);
      acc[p] = fmaf(w1.x, xb.x, acc[p]);
      acc[p] = fmaf(w1.y, xb.y, acc[p]);
      acc[p] = fmaf(w1.z, xb.z, acc[p]);
      acc[p] = fmaf(w1.w, xb.w, acc[p]);
    }
  }
  float4* ov = (float4*)(s_part + ((size_t)chunk * B + b) * (OD * PD) + (size_t)o * PD);
#pragma unroll
  for (int j = 0; j < 4; ++j)
    ov[j] = make_float4(acc[4 * j], acc[4 * j + 1], acc[4 * j + 2], acc[4 * j + 3]);
}

// reduce NCS partials (coalesced), squash per 16-lane p-group via shfl_xor.
__global__ __launch_bounds__(256) void squash_kernel(const float* __restrict__ s_part,
                                                     float* __restrict__ v,
                                                     float* __restrict__ out,
                                                     int write_out) {
  const int t = blockIdx.x * 256 + threadIdx.x;  // < 81920, layout (b*10+o)*16+p
  float sv = 0.f;
#pragma unroll
  for (int ch = 0; ch < NCS; ++ch) sv += s_part[(size_t)ch * SOP + t];
  float sq = sv * sv;
#pragma unroll
  for (int m = 1; m < 16; m <<= 1) sq += __shfl_xor(sq, m, 16);  // sum over p-group
  const float norm = sqrtf(sq + 1e-8f);
  const float val = sv * (sq / ((1.f + sq) * norm));
  v[t] = val;
  if (write_out) out[t] = val;
}

// u_vj1[i,o] = (1/B) sum_{q,p} W[i,o,p,q] * G[q][p],  G[q][p] = sum_b x[b,i,q] v[b,o,p]
// block = (64 i-lanes, 5 o-waves; o looped 2x), grid = (1152/64, NCB)
__global__ __launch_bounds__(320) void agree_kernel(const float* __restrict__ x,
                                                    const float* __restrict__ W,
                                                    const float* __restrict__ v,
                                                    float* __restrict__ u_part) {
  const int i = blockIdx.x * 64 + threadIdx.x;
  const int b0 = blockIdx.y * 64;
  for (int oo = 0; oo < 2; ++oo) {
    const int o = threadIdx.y + 5 * oo;
    float G[QD][PD];
#pragma unroll
    for (int q = 0; q < QD; ++q)
#pragma unroll
      for (int p = 0; p < PD; ++p) G[q][p] = 0.f;
    for (int b = b0; b < b0 + 64; ++b) {
      const float4* vp = (const float4*)(v + ((size_t)b * OD + o) * PD);
      const float4 v0 = vp[0], v1 = vp[1], v2 = vp[2], v3 = vp[3];
      const float vs[PD] = {v0.x, v0.y, v0.z, v0.w, v1.x, v1.y, v1.z, v1.w,
                            v2.x, v2.y, v2.z, v2.w, v3.x, v3.y, v3.z, v3.w};
      const float4* xp = (const float4*)(x + ((size_t)b * IC + i) * QD);
      const float4 xa = xp[0], xb = xp[1];
      const float xs[QD] = {xa.x, xa.y, xa.z, xa.w, xb.x, xb.y, xb.z, xb.w};
#pragma unroll
      for (int q = 0; q < QD; ++q)
#pragma unroll
        for (int p = 0; p < PD; ++p) G[q][p] = fmaf(xs[q], vs[p], G[q][p]);
    }
    const float4* wp = (const float4*)(W + ((size_t)i * OD + o) * PD * QD);
    float u = 0.f;
#pragma unroll
    for (int p = 0; p < PD; ++p) {
      const float4 w0 = wp[2 * p], w1 = wp[2 * p + 1];
      u += w0.x * G[0][p] + w0.y * G[1][p] + w0.z * G[2][p] + w0.w * G[3][p] +
           w1.x * G[4][p] + w1.y * G[5][p] + w1.z * G[6][p] + w1.w * G[7][p];
    }
    u_part[((size_t)blockIdx.y * IC + i) * OD + o] = u * (1.0f / (float)B);
  }
}

// bij += sum_chunk u_part; c = softmax over i (axis 0). One block per o.
__global__ __launch_bounds__(256) void route_kernel(const float* __restrict__ u_part,
                                                    float* __restrict__ bij,
                                                    float* __restrict__ c,
                                                    int add_prev) {
  const int o = blockIdx.x;
  __shared__ float red[256];
  float val[5];
  float lmax = -1e30f;
#pragma unroll
  for (int k = 0; k < 5; ++k) {
    const int i = threadIdx.x + k * 256;
    if (i < IC) {
      float sacc = add_prev ? bij[i * OD + o] : 0.f;
#pragma unroll
      for (int ch = 0; ch < NCB; ++ch) sacc += u_part[((size_t)ch * IC + i) * OD + o];
      val[k] = sacc;
      bij[i * OD + o] = sacc;
      lmax = fmaxf(lmax, sacc);
    } else {
      val[k] = -1e30f;
    }
  }
  red[threadIdx.x] = lmax;
  __syncthreads();
  for (int st = 128; st > 0; st >>= 1) {
    if (threadIdx.x < st) red[threadIdx.x] = fmaxf(red[threadIdx.x], red[threadIdx.x + st]);
    __syncthreads();
  }
  const float gmax = red[0];
  __syncthreads();
  float lsum = 0.f;
#pragma unroll
  for (int k = 0; k < 5; ++k) {
    const int i = threadIdx.x + k * 256;
    if (i < IC) {
      val[k] = __expf(val[k] - gmax);
      lsum += val[k];
    }
  }
  red[threadIdx.x] = lsum;
  __syncthreads();
  for (int st = 128; st > 0; st >>= 1) {
    if (threadIdx.x < st) red[threadIdx.x] += red[threadIdx.x + st];
    __syncthreads();
  }
  const float inv = 1.f / red[0];
#pragma unroll
  for (int k = 0; k < 5; ++k) {
    const int i = threadIdx.x + k * 256;
    if (i < IC) c[i * OD + o] = val[k] * inv;
  }
}

extern "C" void kernel_launch(void* const* d_in, const int* in_sizes, int n_in,
                              void* d_out, int out_size, void* d_ws, size_t ws_size,
                              hipStream_t stream) {
  const float* x = (const float*)d_in[0];  // [512,1152,8] fp32
  const float* W = (const float*)d_in[1];  // [1152,10,16,8] fp32
  float* out = (float*)d_out;              // [512,10,16] fp32

  // workspace layout (fp32): 12.6 MB total — identical footprint to the
  // R1/R2 runs whose intermediates were provably correct, so ws_size fits.
  float* ws = (float*)d_ws;
  float* s_part = ws;                          // NCS * 81920 = 2,949,120
  float* v = s_part + (size_t)NCS * SOP;       // 81920
  float* u_part = v + SOP;                     // NCB*11520 = 92160
  float* bij = u_part + (size_t)NCB * IC * OD; // 11520
  float* c = bij + IC * OD;                    // 11520

  const dim3 sgrid(B / 64, 2, NCS), sblk(64, 5);
  const dim3 agrid(IC / 64, NCB), ablk(64, 5);

  init_c_kernel<<<(IC * OD + 255) / 256, 256, 0, stream>>>(c);
  for (int iter = 0; iter < 3; ++iter) {
    s_kernel<<<sgrid, sblk, 0, stream>>>(x, W, c, s_part);
    squash_kernel<<<SOP / 256, 256, 0, stream>>>(s_part, v, out, iter == 2);
    if (iter < 2) {
      agree_kernel<<<agrid, ablk, 0, stream>>>(x, W, v, u_part);
      route_kernel<<<OD, 256, 0, stream>>>(u_part, bij, c, iter > 0);
    }
  }
}